// Round 5
// baseline (1700.478 us; speedup 1.0000x reference)
//
#include <hip/hip_runtime.h>
#include <hip/hip_bf16.h>
#include <math.h>

#define BATCH   1024
#define SEQ     80
#define EMB     512
#define UNITS   512
#define NBG     64           // batch groups, 16 rows each
#define ROWS    16
#define THREADS 512          // 8 waves; wave w owns cols [w*64, w*64+64)
#define RING    5            // ring depth (throttle slack = RING-1-lag)
#define LDH     520          // LDS row stride (ushort), 16B-aligned rows

typedef __attribute__((ext_vector_type(8))) short              bf16x8;
typedef __attribute__((ext_vector_type(8))) unsigned short     u16x8;
typedef __attribute__((ext_vector_type(4))) float              f32x4;
typedef __attribute__((ext_vector_type(2))) unsigned long long u64x2;

__device__ inline unsigned short f2bf(float f) {
    __hip_bfloat16 h = __float2bfloat16(f);
    return *reinterpret_cast<unsigned short*>(&h);
}
__device__ inline float bf2f(unsigned short u) {
    unsigned int x = ((unsigned int)u) << 16;
    return __uint_as_float(x);
}
__device__ inline float tanh_fast(float x) {
    float e = __expf(2.f * x);
    return 1.f - 2.f / (e + 1.f);
}
__device__ inline u16x8 pack8(float4 p0, float4 p1) {
    u16x8 v;
    v[0]=f2bf(p0.x); v[1]=f2bf(p0.y); v[2]=f2bf(p0.z); v[3]=f2bf(p0.w);
    v[4]=f2bf(p1.x); v[5]=f2bf(p1.y); v[6]=f2bf(p1.z); v[7]=f2bf(p1.w);
    return v;
}
__device__ inline void st_f32(float* p, float v) {
    __hip_atomic_store(p, v, __ATOMIC_RELAXED, __HIP_MEMORY_SCOPE_AGENT);
}
__device__ inline void st_u16(unsigned short* p, unsigned short v) {
    __hip_atomic_store(p, v, __ATOMIC_RELAXED, __HIP_MEMORY_SCOPE_AGENT);
}
__device__ inline float ld_f32(const float* p) {
    return __hip_atomic_load(p, __ATOMIC_RELAXED, __HIP_MEMORY_SCOPE_AGENT);
}
__device__ inline unsigned long long ld_u64(const unsigned long long* p) {
    return __hip_atomic_load(p, __ATOMIC_RELAXED, __HIP_MEMORY_SCOPE_AGENT);
}
__device__ inline int ld_flag(const int* p) {
    return __hip_atomic_load(p, __ATOMIC_RELAXED, __HIP_MEMORY_SCOPE_AGENT);
}

// ---------------------------------------------------------------------------
// Pack weights into per-(matrix, wave, ntile) B-fragment slabs, bf16.
// g = ((m*8 + w)*4 + nt)*16 + k ; elem(lane,j) = Wm[k*32+(lane>>4)*8+j][w*64+nt*16+(lane&15)]
// m: 0=W0x (preX), 1=W0h (h0), 2=W1x (u), 3=W1h (h1). Stage id == m.
// ---------------------------------------------------------------------------
__global__ __launch_bounds__(256) void pack_weights(
    const float* __restrict__ W0x, const float* __restrict__ W0h,
    const float* __restrict__ W1x, const float* __restrict__ W1h,
    unsigned short* __restrict__ wpack)
{
    int g    = blockIdx.x * 4 + (threadIdx.x >> 6);   // 0..2047
    int lane = threadIdx.x & 63;
    int m    = g >> 9;
    int w    = (g >> 6) & 7;
    int nt   = (g >> 4) & 3;
    int k    = g & 15;
    int col  = w * 64 + nt * 16 + (lane & 15);
    int rowb = k * 32 + (lane >> 4) * 8;
    const float* src = (m == 0) ? W0x : (m == 1) ? W0h : (m == 2) ? W1x : W1h;

    u16x8 v;
#pragma unroll
    for (int j = 0; j < 8; ++j)
        v[j] = f2bf(src[(size_t)(rowb + j) * UNITS + col]);
    *(u16x8*)(wpack + (size_t)g * 512 + lane * 8) = v;
}

// one n-tile GEMM: acc += A(av[16]) @ 16 B-slabs streamed depth-8 from L2
#define NT_GEMM(ACC, WN)                                                       \
    do {                                                                       \
        bf16x8 Bf_[8];                                                         \
        _Pragma("unroll")                                                      \
        for (int i_ = 0; i_ < 8; ++i_)                                         \
            Bf_[i_] = *(const bf16x8*)((WN) + (size_t)i_ * 512);               \
        _Pragma("unroll")                                                      \
        for (int k_ = 0; k_ < 16; ++k_) {                                      \
            bf16x8 b_ = Bf_[k_ & 7];                                           \
            if (k_ + 8 < 16)                                                   \
                Bf_[k_ & 7] = *(const bf16x8*)((WN) + (size_t)(k_ + 8) * 512); \
            ACC = __builtin_amdgcn_mfma_f32_16x16x32_bf16(av[k_], b_, ACC,     \
                                                          0, 0, 0);            \
        }                                                                      \
    } while (0)

// ---------------------------------------------------------------------------
// 256 blocks = 4 stages x 64 bg, co-resident (1/CU). Stage owns 16 rows x ALL
// 512 cols -> recurrences (h0,h1) are fully in-block; inter-stage links are
// one-directional rings (depth RING) with monotone flags.
// Flag convention: F_s = t means stage s completed steps <= t-1 AND their ring
// publishes are globally visible (release follows the syncthreads that drains
// the previous step's stores). Throttle: producer of ring slot t%RING spins
// consumer flag >= t-RING+1 before overwriting (slack ~2 in steady state).
// ---------------------------------------------------------------------------
__global__ __launch_bounds__(THREADS, 2) void rnn_pipe(
    const int*   __restrict__ inputs,
    const float* __restrict__ emb,
    const float* __restrict__ b0,
    const float* __restrict__ b1,
    const unsigned short* __restrict__ wpack,
    float*          __restrict__ pxring,   // [RING][64][16][512] f32
    unsigned short* __restrict__ h0ring,   // [RING][64][16][512] bf16
    float*          __restrict__ uring,    // [RING][64][16][512] f32
    int*            __restrict__ flg,      // [4][64]
    const float* __restrict__ Wout,
    const float* __restrict__ bout,
    float*       __restrict__ out)
{
    __shared__ __align__(16) unsigned short sA[2 * ROWS * LDH];

    const int tid   = threadIdx.x;
    const int w     = tid >> 6;
    const int lane  = tid & 63;
    const int quad  = lane >> 4;
    const int l15   = lane & 15;
    const int stage = blockIdx.x >> 6;    // == matrix id m
    const int bg    = blockIdx.x & 63;
    const int rbase = bg * ROWS;

    const int gr   = w;                   // staging rows w, w+8
    const int gc   = lane * 8;            // ushort col of 16B unit
    const int aoff = l15 * LDH + quad * 8;
    const int col0 = w * 64 + l15;        // + nt*16

    int* Fpx = flg;
    int* Fh0 = flg + 64;
    int* Fu  = flg + 128;
    int* Fh1 = flg + 192;

    const unsigned short* wb = wpack + ((size_t)((stage * 8 + w) * 64)) * 512
                                     + lane * 8;

    // =====================================================================
    if (stage == 0) {                     // ---- preX: b0 + x_t @ W0x ----
        float bb[4];
#pragma unroll
        for (int nt = 0; nt < 4; ++nt) bb[nt] = b0[col0 + nt * 16];

        for (int t = 0; t < SEQ; ++t) {
            if (tid == 0)
                while (ld_flag(&Fh0[bg]) < t - (RING - 1))
                    __builtin_amdgcn_s_sleep(1);
            __asm__ volatile("" ::: "memory");
            __syncthreads();                       // drains step t-1 publishes
            if (tid == 0)
                __hip_atomic_store(&Fpx[bg], t, __ATOMIC_RELEASE,
                                   __HIP_MEMORY_SCOPE_AGENT);
            // gather x_t -> sA rows gr, gr+8
            {
                int ia = inputs[(rbase + gr) * SEQ + t];
                int ib = inputs[(rbase + gr + 8) * SEQ + t];
                const float4* ea = (const float4*)(emb + (size_t)ia * EMB + gc);
                const float4* eb = (const float4*)(emb + (size_t)ib * EMB + gc);
                float4 f0 = ea[0], f1 = ea[1], f2 = eb[0], f3 = eb[1];
                *(u16x8*)(sA + gr * LDH + gc)       = pack8(f0, f1);
                *(u16x8*)(sA + (gr + 8) * LDH + gc) = pack8(f2, f3);
            }
            __syncthreads();                       // x writes -> A reads

            bf16x8 av[16];
            const unsigned short* ar = sA + aoff;
#pragma unroll
            for (int k = 0; k < 16; ++k) av[k] = *(const bf16x8*)(ar + k * 32);

            f32x4 acc[4];
#pragma unroll
            for (int nt = 0; nt < 4; ++nt) {
                acc[nt] = (f32x4){bb[nt], bb[nt], bb[nt], bb[nt]};
                NT_GEMM(acc[nt], wb + (size_t)(nt * 16) * 512);
            }
            float* dst = pxring + ((size_t)(t % RING) * NBG + bg) * 8192;
#pragma unroll
            for (int nt = 0; nt < 4; ++nt)
#pragma unroll
                for (int i = 0; i < 4; ++i)
                    st_f32(dst + (quad * 4 + i) * 512 + col0 + nt * 16,
                           acc[nt][i]);
        }
        __syncthreads();
        if (tid == 0)
            __hip_atomic_store(&Fpx[bg], SEQ + 1, __ATOMIC_RELEASE,
                               __HIP_MEMORY_SCOPE_AGENT);

    // =====================================================================
    } else if (stage == 1) {              // ---- h0 recurrence ----
        for (int i = tid; i < ROWS * LDH; i += THREADS)
            sA[ROWS * LDH + i] = 0;       // h0(-1) = 0 in buf 1

        for (int t = 0; t < SEQ; ++t) {
            const int par = t & 1, slot = t % RING;
            if (tid == 0) {
                while (ld_flag(&Fu[bg])  < t - (RING - 1)) __builtin_amdgcn_s_sleep(1);
                while (ld_flag(&Fpx[bg]) < t + 1)          __builtin_amdgcn_s_sleep(1);
            }
            __asm__ volatile("" ::: "memory");
            __syncthreads();
            if (tid == 0)
                __hip_atomic_store(&Fh0[bg], t, __ATOMIC_RELEASE,
                                   __HIP_MEMORY_SCOPE_AGENT);
            // acc init = preX(t)
            const float* ps = pxring + ((size_t)slot * NBG + bg) * 8192;
            f32x4 acc[4];
#pragma unroll
            for (int nt = 0; nt < 4; ++nt)
#pragma unroll
                for (int i = 0; i < 4; ++i)
                    acc[nt][i] = ld_f32(ps + (quad * 4 + i) * 512 + col0 + nt * 16);

            bf16x8 av[16];
            const unsigned short* ar = sA + (par ^ 1) * ROWS * LDH + aoff;
#pragma unroll
            for (int k = 0; k < 16; ++k) av[k] = *(const bf16x8*)(ar + k * 32);
#pragma unroll
            for (int nt = 0; nt < 4; ++nt)
                NT_GEMM(acc[nt], wb + (size_t)(nt * 16) * 512);

            unsigned short* hd = sA + par * ROWS * LDH;
            unsigned short* rs = h0ring + ((size_t)slot * NBG + bg) * 8192;
#pragma unroll
            for (int nt = 0; nt < 4; ++nt)
#pragma unroll
                for (int i = 0; i < 4; ++i) {
                    unsigned short hv = f2bf(tanh_fast(acc[nt][i]));
                    hd[(quad * 4 + i) * LDH + col0 + nt * 16] = hv;
                    st_u16(rs + (quad * 4 + i) * 512 + col0 + nt * 16, hv);
                }
        }
        __syncthreads();
        if (tid == 0)
            __hip_atomic_store(&Fh0[bg], SEQ + 1, __ATOMIC_RELEASE,
                               __HIP_MEMORY_SCOPE_AGENT);

    // =====================================================================
    } else if (stage == 2) {              // ---- u = b1 + h0(t) @ W1x ----
        float bb[4];
#pragma unroll
        for (int nt = 0; nt < 4; ++nt) bb[nt] = b1[col0 + nt * 16];

        for (int t = 0; t < SEQ; ++t) {
            const int slot = t % RING;
            if (tid == 0) {
                while (ld_flag(&Fh1[bg]) < t - (RING - 1)) __builtin_amdgcn_s_sleep(1);
                while (ld_flag(&Fh0[bg]) < t + 1)          __builtin_amdgcn_s_sleep(1);
            }
            __asm__ volatile("" ::: "memory");
            __syncthreads();
            if (tid == 0)
                __hip_atomic_store(&Fu[bg], t, __ATOMIC_RELEASE,
                                   __HIP_MEMORY_SCOPE_AGENT);
            // A-frags straight from h0 ring (u64 atomic pairs)
            const unsigned long long* hs = (const unsigned long long*)
                (h0ring + ((size_t)slot * NBG + bg) * 8192);
            bf16x8 av[16];
#pragma unroll
            for (int k = 0; k < 16; ++k) {
                int eo = l15 * 512 + k * 32 + quad * 8;   // ushort offset
                u64x2 q;
                q[0] = ld_u64(hs + (eo >> 2));
                q[1] = ld_u64(hs + (eo >> 2) + 1);
                av[k] = *(bf16x8*)&q;
            }
            f32x4 acc[4];
#pragma unroll
            for (int nt = 0; nt < 4; ++nt) {
                acc[nt] = (f32x4){bb[nt], bb[nt], bb[nt], bb[nt]};
                NT_GEMM(acc[nt], wb + (size_t)(nt * 16) * 512);
            }
            float* dst = uring + ((size_t)slot * NBG + bg) * 8192;
#pragma unroll
            for (int nt = 0; nt < 4; ++nt)
#pragma unroll
                for (int i = 0; i < 4; ++i)
                    st_f32(dst + (quad * 4 + i) * 512 + col0 + nt * 16,
                           acc[nt][i]);
        }
        __syncthreads();
        if (tid == 0)
            __hip_atomic_store(&Fu[bg], SEQ + 1, __ATOMIC_RELEASE,
                               __HIP_MEMORY_SCOPE_AGENT);

    // =====================================================================
    } else {                              // ---- h1 recurrence + epilogue ----
        for (int i = tid; i < ROWS * LDH; i += THREADS)
            sA[ROWS * LDH + i] = 0;       // h1(-1) = 0 in buf 1

        for (int t = 0; t < SEQ; ++t) {
            const int par = t & 1, slot = t % RING;
            if (tid == 0)
                while (ld_flag(&Fu[bg]) < t + 1) __builtin_amdgcn_s_sleep(1);
            __asm__ volatile("" ::: "memory");
            __syncthreads();
            if (tid == 0)
                __hip_atomic_store(&Fh1[bg], t, __ATOMIC_RELEASE,
                                   __HIP_MEMORY_SCOPE_AGENT);
            const float* us = uring + ((size_t)slot * NBG + bg) * 8192;
            f32x4 acc[4];
#pragma unroll
            for (int nt = 0; nt < 4; ++nt)
#pragma unroll
                for (int i = 0; i < 4; ++i)
                    acc[nt][i] = ld_f32(us + (quad * 4 + i) * 512 + col0 + nt * 16);

            bf16x8 av[16];
            const unsigned short* ar = sA + (par ^ 1) * ROWS * LDH + aoff;
#pragma unroll
            for (int k = 0; k < 16; ++k) av[k] = *(const bf16x8*)(ar + k * 32);
#pragma unroll
            for (int nt = 0; nt < 4; ++nt)
                NT_GEMM(acc[nt], wb + (size_t)(nt * 16) * 512);

            unsigned short* hd = sA + par * ROWS * LDH;
#pragma unroll
            for (int nt = 0; nt < 4; ++nt)
#pragma unroll
                for (int i = 0; i < 4; ++i)
                    hd[(quad * 4 + i) * LDH + col0 + nt * 16] =
                        f2bf(tanh_fast(acc[nt][i]));
        }
        __syncthreads();
        if (tid == 0)
            __hip_atomic_store(&Fh1[bg], SEQ + 1, __ATOMIC_RELEASE,
                               __HIP_MEMORY_SCOPE_AGENT);

        // epilogue: out = sigmoid(h1(79) @ Wout + bout); h1(79) in buf 1
        const unsigned short* h1l = sA + ((SEQ - 1) & 1) * ROWS * LDH;
#pragma unroll
        for (int rr = 0; rr < 2; ++rr) {
            int r = w * 2 + rr;
            float s = 0.f;
#pragma unroll
            for (int j = 0; j < 8; ++j) {
                int c = lane + 64 * j;
                s += bf2f(h1l[r * LDH + c]) * Wout[c];
            }
#pragma unroll
            for (int off = 32; off > 0; off >>= 1) s += __shfl_down(s, off);
            if (lane == 0) {
                float z = s + bout[0];
                out[rbase + r] = 1.f / (1.f + __expf(-z));
            }
        }
    }
}

extern "C" void kernel_launch(void* const* d_in, const int* in_sizes, int n_in,
                              void* d_out, int out_size, void* d_ws, size_t ws_size,
                              hipStream_t stream) {
    const int*   inputs = (const int*)d_in[0];
    const float* emb    = (const float*)d_in[1];
    const float* W0x    = (const float*)d_in[2];
    const float* W0h    = (const float*)d_in[3];
    const float* b0     = (const float*)d_in[4];
    const float* W1x    = (const float*)d_in[5];
    const float* W1h    = (const float*)d_in[6];
    const float* b1     = (const float*)d_in[7];
    const float* Wout   = (const float*)d_in[8];
    const float* bout   = (const float*)d_in[9];
    float*       out    = (float*)d_out;

    char* base = (char*)d_ws;
    const size_t WP_OFF = 0;                                  // 2 MB wpack
    const size_t PX_OFF = (size_t)2  * 1024 * 1024;           // 10 MB f32 ring
    const size_t H0_OFF = PX_OFF + (size_t)RING * 2097152;    //  5 MB bf16 ring
    const size_t U_OFF  = H0_OFF + (size_t)RING * 1048576;    // 10 MB f32 ring
    const size_t FL_OFF = U_OFF  + (size_t)RING * 2097152;    //  flags

    unsigned short* wpack  = (unsigned short*)(base + WP_OFF);
    float*          pxring = (float*)(base + PX_OFF);
    unsigned short* h0ring = (unsigned short*)(base + H0_OFF);
    float*          uring  = (float*)(base + U_OFF);
    int*            flg    = (int*)(base + FL_OFF);

    hipMemsetAsync(flg, 0, 2048, stream);
    pack_weights<<<512, 256, 0, stream>>>(W0x, W0h, W1x, W1h, wpack);
    rnn_pipe<<<4 * NBG, THREADS, 0, stream>>>(
        inputs, emb, b0, b1, wpack, pxring, h0ring, uring, flg,
        Wout, bout, out);
}

// Round 6
// 1215.176 us; speedup vs baseline: 1.3994x; 1.3994x over previous
//
#include <hip/hip_runtime.h>
#include <hip/hip_bf16.h>
#include <math.h>

#define BATCH   1024
#define SEQ     80
#define EMB     512
#define UNITS   512
#define NBG     64           // batch groups (16 rows each)
#define NCG     4            // col groups (128 cols each)
#define ROWS    16
#define COLS    128
#define THREADS 512          // 8 waves; wave w owns col tile [cg*128 + w*16, +16)
#define LDX     520          // x LDS row stride (ushort)
#define LDG     1032         // gathered-h LDS row stride (ushort): h0g[0..511]|h1g[512..1023]
#define XELE    (ROWS * LDX) // one x buffer

#define H0_OFF   (2u * 1024 * 1024)
#define H1_OFF   (4u * 1024 * 1024)
#define FLAG_OFF (6u * 1024 * 1024)

typedef __attribute__((ext_vector_type(8))) short              bf16x8;
typedef __attribute__((ext_vector_type(8))) unsigned short     u16x8;
typedef __attribute__((ext_vector_type(4))) float              f32x4;
typedef __attribute__((ext_vector_type(2))) unsigned long long u64x2;

__device__ inline unsigned short f2bf(float f) {
    __hip_bfloat16 h = __float2bfloat16(f);
    return *reinterpret_cast<unsigned short*>(&h);
}
__device__ inline float bf2f(unsigned short u) {
    unsigned int x = ((unsigned int)u) << 16;
    return __uint_as_float(x);
}
__device__ inline float tanh_fast(float x) {
    float e = __expf(2.f * x);
    return 1.f - 2.f / (e + 1.f);
}
__device__ inline u16x8 pack8(float4 p0, float4 p1) {
    u16x8 v;
    v[0]=f2bf(p0.x); v[1]=f2bf(p0.y); v[2]=f2bf(p0.z); v[3]=f2bf(p0.w);
    v[4]=f2bf(p1.x); v[5]=f2bf(p1.y); v[6]=f2bf(p1.z); v[7]=f2bf(p1.w);
    return v;
}

// ---------------------------------------------------------------------------
// Pack weights into per-(phase, cg, wave) contiguous B-fragment slabs, bf16.
// slab id g = ((p*NCG + cg)*8 + w)*32 + k0 ; elem = g*512 + lane*8 + j
// value = Wp[k0*32 + (lane>>4)*8 + j][cg*128 + w*16 + (lane&15)]
// Wp rows: [Wx ; Wh] stacked (K=1024).  (identical to validated baseline)
// ---------------------------------------------------------------------------
__global__ __launch_bounds__(256) void pack_weights(
    const float* __restrict__ W0x, const float* __restrict__ W0h,
    const float* __restrict__ W1x, const float* __restrict__ W1h,
    unsigned short* __restrict__ wpack)
{
    int g    = blockIdx.x * 4 + (threadIdx.x >> 6);   // 0..2047
    int lane = threadIdx.x & 63;
    int p    = g >> 10;
    int cg   = (g >> 8) & 3;
    int w    = (g >> 5) & 7;
    int k0   = g & 31;
    int n    = cg * COLS + w * 16 + (lane & 15);
    int kb   = k0 * 32 + (lane >> 4) * 8;
    const float* Wx = p ? W1x : W0x;
    const float* Wh = p ? W1h : W0h;

    u16x8 v;
#pragma unroll
    for (int j = 0; j < 8; ++j) {
        int k = kb + j;
        float f = (k < 512) ? Wx[(size_t)k * UNITS + n]
                            : Wh[(size_t)(k - 512) * UNITS + n];
        v[j] = f2bf(f);
    }
    *(u16x8*)(wpack + (size_t)g * 512 + lane * 8) = v;
}

// K=512 GEMM: A-frags from LDS (APTR, row stride baked into APTR), 16 B-slabs
// streamed depth-8 from L2 (validated pattern)
#define RUN_STREAM(ACC, APTR, WB)                                              \
    do {                                                                       \
        const unsigned short* a_lds_ = (APTR);                                 \
        bf16x8 Bf_[8];                                                         \
        _Pragma("unroll")                                                      \
        for (int i_ = 0; i_ < 8; ++i_)                                         \
            Bf_[i_] = *(const bf16x8*)((WB) + (size_t)i_ * 512);               \
        _Pragma("unroll")                                                      \
        for (int k0_ = 0; k0_ < 16; ++k0_) {                                   \
            bf16x8 a_ = *(const bf16x8*)(a_lds_ + k0_ * 32);                   \
            bf16x8 b_ = Bf_[k0_ & 7];                                          \
            if (k0_ + 8 < 16)                                                  \
                Bf_[k0_ & 7] = *(const bf16x8*)((WB) + (size_t)(k0_ + 8)*512); \
            ACC = __builtin_amdgcn_mfma_f32_16x16x32_bf16(a_, b_, ACC, 0,0,0); \
        }                                                                      \
    } while (0)

// stage x_T into XB (wave w rows w, w+8; 16B col units)
#define STAGE_X(TT, XB)                                                        \
    do {                                                                       \
        int tn_ = (TT) < SEQ ? (TT) : SEQ - 1;                                 \
        int ia_ = inputs[(rbase + gr) * SEQ + tn_];                            \
        int ib_ = inputs[(rbase + gr + 8) * SEQ + tn_];                        \
        const float4* ea_ = (const float4*)(emb + (size_t)ia_ * EMB + gc);     \
        const float4* eb_ = (const float4*)(emb + (size_t)ib_ * EMB + gc);     \
        float4 f0_ = ea_[0], f1_ = ea_[1], f2_ = eb_[0], f3_ = eb_[1];         \
        *(u16x8*)((XB) + gr * LDX + gc)       = pack8(f0_, f1_);               \
        *(u16x8*)((XB) + (gr + 8) * LDX + gc) = pack8(f2_, f3_);               \
    } while (0)

// ---------------------------------------------------------------------------
// 256 blocks = 64 bg x 4 cg, co-resident (1/CU). Block: 16 rows x 128 cols.
// FUSED exchange: ONE flag round per step (81 total, vs baseline's 160).
// Round r: spin>=r -> gather h0(r-1),h1(r-2) (parity r^1) -> critical:
//   h0(r)   = tanh(preX(r) + h0(r-1)g @ W0h)            [publish, r<SEQ]
//   h1(r-1) = tanh(h0(r-1)g @ W1x + h1(r-2)g @ W1h + b1) [publish, r>0]
// -> barrier (drains publishes) -> flag=r+1 -> shadow: stage x(r+2),
//   preX(r+1) = b0 + x(r+1) @ W0x.
// h1 lags h0 by one round (same recurrence, computed one round late).
// Publish/spin/fence/barrier protocol identical to the validated baseline.
// ---------------------------------------------------------------------------
__global__ __launch_bounds__(THREADS, 1) void rnn_fused(
    const int*   __restrict__ inputs,
    const float* __restrict__ emb,
    const float* __restrict__ b0,
    const float* __restrict__ b1,
    const unsigned short* __restrict__ wpack,
    unsigned short* __restrict__ h0buf,   // [2][1024][512] bf16
    unsigned short* __restrict__ h1buf,   // [2][1024][512] bf16 (parity 0 pre-zeroed)
    int* __restrict__ flags,              // [64][4]
    const float* __restrict__ Wout,
    const float* __restrict__ bout,
    float*       __restrict__ out)
{
    __shared__ __align__(16) unsigned short xb[2 * XELE];     // x(t), x(t+1)
    __shared__ __align__(16) unsigned short hg[ROWS * LDG];   // h0g | h1g

    const int tid   = threadIdx.x;
    const int w     = tid >> 6;
    const int lane  = tid & 63;
    const int quad  = lane >> 4;
    const int l15   = lane & 15;
    const int cg    = blockIdx.x >> 6;    // 0..3
    const int bg    = blockIdx.x & 63;    // 0..63
    const int rbase = bg * ROWS;

    const int gr = w;                     // staging/gather rows w, w+8
    const int gc = (tid & 63) * 8;        // ushort col of this thread's 16B unit

    const int   mycol = cg * COLS + w * 16 + l15;
    const float bias0 = b0[mycol];
    const float bias1 = b1[mycol];

    const unsigned short* wb0  = wpack + ((size_t)(cg * 256 + w * 32)) * 512 + lane * 8;
    const unsigned short* wb1  = wb0 + (size_t)1024 * 512;
    const unsigned short* wb0x = wb0;                        // p0 slabs  0..15: W0x
    const unsigned short* wb0h = wb0 + (size_t)16 * 512;     // p0 slabs 16..31: W0h
    const unsigned short* wb1x = wb1;                        // p1 slabs  0..15: W1x
    const unsigned short* wb1h = wb1 + (size_t)16 * 512;     // p1 slabs 16..31: W1h

    const unsigned short* aH0 = hg + l15 * LDG + quad * 8;         // h0g A-frags
    const unsigned short* aH1 = hg + l15 * LDG + 512 + quad * 8;   // h1g A-frags
    const int axoff = l15 * LDX + quad * 8;                        // x A-frags
    const int fl    = bg * NCG;

    // ---- prologue: zero hg; stage x(0)->xb[0], x(1)->xb[1]; preX(0) ----
    for (int i = tid; i < ROWS * LDG; i += THREADS) hg[i] = 0;
    STAGE_X(0, xb);
    STAGE_X(1, xb + XELE);
    __syncthreads();

    f32x4 preX = {bias0, bias0, bias0, bias0};
    RUN_STREAM(preX, xb + axoff, wb0x);               // preX(0) = b0 + x0@W0x

    for (int r = 0; r <= SEQ; ++r) {
        const int par = r & 1;

        if (tid < NCG)
            while (__hip_atomic_load(&flags[fl + tid],
                                     __ATOMIC_RELAXED, __HIP_MEMORY_SCOPE_AGENT) < r)
                __builtin_amdgcn_s_sleep(1);
        __asm__ volatile("" ::: "memory");
        __syncthreads();                                              // B1

        if (r > 0) {
            // gather h0(r-1) -> hg[0..511], h1(r-2) -> hg[512..1023]
            const unsigned long long* s0 = (const unsigned long long*)
                (h0buf + ((size_t)(par ^ 1) * BATCH + rbase) * UNITS);
            const unsigned long long* s1 = (const unsigned long long*)
                (h1buf + ((size_t)(par ^ 1) * BATCH + rbase) * UNITS);
            int ua = gr * 128 + (tid & 63) * 2;
            int ub = ua + 8 * 128;
            unsigned long long q0 = __hip_atomic_load(s0 + ua,     __ATOMIC_RELAXED, __HIP_MEMORY_SCOPE_AGENT);
            unsigned long long q1 = __hip_atomic_load(s0 + ua + 1, __ATOMIC_RELAXED, __HIP_MEMORY_SCOPE_AGENT);
            unsigned long long q2 = __hip_atomic_load(s0 + ub,     __ATOMIC_RELAXED, __HIP_MEMORY_SCOPE_AGENT);
            unsigned long long q3 = __hip_atomic_load(s0 + ub + 1, __ATOMIC_RELAXED, __HIP_MEMORY_SCOPE_AGENT);
            unsigned long long q4 = __hip_atomic_load(s1 + ua,     __ATOMIC_RELAXED, __HIP_MEMORY_SCOPE_AGENT);
            unsigned long long q5 = __hip_atomic_load(s1 + ua + 1, __ATOMIC_RELAXED, __HIP_MEMORY_SCOPE_AGENT);
            unsigned long long q6 = __hip_atomic_load(s1 + ub,     __ATOMIC_RELAXED, __HIP_MEMORY_SCOPE_AGENT);
            unsigned long long q7 = __hip_atomic_load(s1 + ub + 1, __ATOMIC_RELAXED, __HIP_MEMORY_SCOPE_AGENT);
            u64x2 v0; v0[0] = q0; v0[1] = q1;
            u64x2 v1; v1[0] = q2; v1[1] = q3;
            u64x2 v2; v2[0] = q4; v2[1] = q5;
            u64x2 v3; v3[0] = q6; v3[1] = q7;
            *(u64x2*)(hg + gr * LDG + gc)             = v0;
            *(u64x2*)(hg + (gr + 8) * LDG + gc)       = v1;
            *(u64x2*)(hg + gr * LDG + 512 + gc)       = v2;
            *(u64x2*)(hg + (gr + 8) * LDG + 512 + gc) = v3;
        }
        __syncthreads();                                              // B2

        // ---- critical: h0(r) then h1(r-1), publish each ASAP ----
        if (r < SEQ) {
            f32x4 acc0 = preX;
            RUN_STREAM(acc0, aH0, wb0h);              // + h0(r-1)g @ W0h
            unsigned short* dst = h0buf +
                ((size_t)par * BATCH + rbase + quad * 4) * UNITS + mycol;
#pragma unroll
            for (int i = 0; i < 4; ++i)
                __hip_atomic_store(dst + (size_t)i * UNITS,
                                   f2bf(tanh_fast(acc0[i])),
                                   __ATOMIC_RELAXED, __HIP_MEMORY_SCOPE_AGENT);
        }
        if (r > 0) {
            f32x4 acc1 = {bias1, bias1, bias1, bias1};
            RUN_STREAM(acc1, aH0, wb1x);              // + h0(r-1)g @ W1x
            RUN_STREAM(acc1, aH1, wb1h);              // + h1(r-2)g @ W1h
            unsigned short* dst = h1buf +
                ((size_t)par * BATCH + rbase + quad * 4) * UNITS + mycol;
#pragma unroll
            for (int i = 0; i < 4; ++i)
                __hip_atomic_store(dst + (size_t)i * UNITS,
                                   f2bf(tanh_fast(acc1[i])),
                                   __ATOMIC_RELAXED, __HIP_MEMORY_SCOPE_AGENT);
        }
        __syncthreads();                                              // B3 (drain)
        if (tid == 0)
            __hip_atomic_store(&flags[fl + cg], r + 1,
                               __ATOMIC_RELEASE, __HIP_MEMORY_SCOPE_AGENT);

        // ---- shadow (hides sibling flag RT): stage x(r+2), preX(r+1) ----
        if (r < SEQ) {
            STAGE_X(r + 2, xb + par * XELE);          // x(r+2) -> xb[(r+2)&1]
            preX = (f32x4){bias0, bias0, bias0, bias0};
            RUN_STREAM(preX, xb + (par ^ 1) * XELE + axoff, wb0x); // x(r+1)@W0x
        }
    }

    // ---- epilogue: cg0 gathers h1(79) (parity SEQ&1=0) and writes out ----
    if (cg == 0) {
        if (tid < NCG)
            while (__hip_atomic_load(&flags[fl + tid],
                                     __ATOMIC_RELAXED, __HIP_MEMORY_SCOPE_AGENT) < SEQ + 1)
                __builtin_amdgcn_s_sleep(1);
        __asm__ volatile("" ::: "memory");
        __syncthreads();
        {
            const unsigned long long* s1 = (const unsigned long long*)
                (h1buf + ((size_t)(SEQ & 1) * BATCH + rbase) * UNITS);
            int ua = gr * 128 + (tid & 63) * 2;
            int ub = ua + 8 * 128;
            unsigned long long q0 = __hip_atomic_load(s1 + ua,     __ATOMIC_RELAXED, __HIP_MEMORY_SCOPE_AGENT);
            unsigned long long q1 = __hip_atomic_load(s1 + ua + 1, __ATOMIC_RELAXED, __HIP_MEMORY_SCOPE_AGENT);
            unsigned long long q2 = __hip_atomic_load(s1 + ub,     __ATOMIC_RELAXED, __HIP_MEMORY_SCOPE_AGENT);
            unsigned long long q3 = __hip_atomic_load(s1 + ub + 1, __ATOMIC_RELAXED, __HIP_MEMORY_SCOPE_AGENT);
            u64x2 v0; v0[0] = q0; v0[1] = q1;
            u64x2 v1; v1[0] = q2; v1[1] = q3;
            *(u64x2*)(hg + gr * LDG + gc)       = v0;
            *(u64x2*)(hg + (gr + 8) * LDG + gc) = v1;
        }
        __syncthreads();
#pragma unroll
        for (int rr = 0; rr < 2; ++rr) {
            int r2 = w * 2 + rr;
            float s = 0.f;
#pragma unroll
            for (int j = 0; j < 8; ++j) {
                int c = lane + 64 * j;
                s += bf2f(hg[r2 * LDG + c]) * Wout[c];
            }
#pragma unroll
            for (int off = 32; off > 0; off >>= 1) s += __shfl_down(s, off);
            if (lane == 0) {
                float z = s + bout[0];
                out[rbase + r2] = 1.f / (1.f + __expf(-z));
            }
        }
    }
}

extern "C" void kernel_launch(void* const* d_in, const int* in_sizes, int n_in,
                              void* d_out, int out_size, void* d_ws, size_t ws_size,
                              hipStream_t stream) {
    const int*   inputs = (const int*)d_in[0];
    const float* emb    = (const float*)d_in[1];
    const float* W0x    = (const float*)d_in[2];
    const float* W0h    = (const float*)d_in[3];
    const float* b0     = (const float*)d_in[4];
    const float* W1x    = (const float*)d_in[5];
    const float* W1h    = (const float*)d_in[6];
    const float* b1     = (const float*)d_in[7];
    const float* Wout   = (const float*)d_in[8];
    const float* bout   = (const float*)d_in[9];
    float*       out    = (float*)d_out;

    unsigned short* wpack = (unsigned short*)d_ws;                      // 2 MB
    unsigned short* h0buf = (unsigned short*)((char*)d_ws + H0_OFF);    // 2 MB
    unsigned short* h1buf = (unsigned short*)((char*)d_ws + H1_OFF);    // 2 MB
    int* flags = (int*)((char*)d_ws + FLAG_OFF);                        // 1 KB

    hipMemsetAsync(flags, 0, 2048, stream);
    hipMemsetAsync(h1buf, 0, (size_t)BATCH * UNITS * sizeof(unsigned short),
                   stream);                       // h1 parity 0 = h1(-1) = 0
    pack_weights<<<512, 256, 0, stream>>>(W0x, W0h, W1x, W1h, wpack);
    rnn_fused<<<NBG * NCG, THREADS, 0, stream>>>(
        inputs, emb, b0, b1, wpack, h0buf, h1buf, flags,
        Wout, bout, out);
}